// Round 10
// baseline (52.196 us; speedup 1.0000x reference)
//
#include <hip/hip_runtime.h>

typedef __attribute__((ext_vector_type(8))) short short8;
typedef __attribute__((ext_vector_type(16))) float f32x16;
typedef unsigned short ushort_t;

#define MFMA(A, B, C) __builtin_amdgcn_mfma_f32_32x32x16_bf16(A, B, C, 0, 0, 0)

__device__ __forceinline__ float4 ldf4(const float* p) { return *(const float4*)p; }
__device__ __forceinline__ short8 ld8(const void* p) { return *(const short8*)p; }

__device__ __forceinline__ short8 mk8(unsigned w0, unsigned w1, unsigned w2, unsigned w3) {
    union { unsigned u[4]; short8 s; } t;
    t.u[0] = w0; t.u[1] = w1; t.u[2] = w2; t.u[3] = w3;
    return t.s;
}
// pack bf16-truncations of (a,b): low16 = top16(a), high16 = top16(b)
__device__ __forceinline__ unsigned packhi2(float a, float b) {
    return __builtin_amdgcn_perm(__float_as_uint(b), __float_as_uint(a), 0x07060302u);
}
__device__ __forceinline__ float lopart(float v) {
    return v - __uint_as_float(__float_as_uint(v) & 0xFFFF0000u);
}
// v_permlane32_swap: lo' = [lo_lo, hi_lo], hi' = [lo_hi, hi_hi]
__device__ __forceinline__ void plswap(unsigned& lo, unsigned& hi) {
    asm("v_permlane32_swap_b32 %0, %1" : "+v"(lo), "+v"(hi));
}
__device__ __forceinline__ ushort_t h16(float x) { return (ushort_t)(__float_as_uint(x) >> 16); }
__device__ __forceinline__ float fh(ushort_t u) { return __uint_as_float(((unsigned)u) << 16); }

// async global->LDS, 16 B per lane; lds base wave-uniform, gsrc per-lane
__device__ __forceinline__ void dma16(const float* g, void* l) {
    __builtin_amdgcn_global_load_lds((const __attribute__((address_space(1))) void*)g,
                                     (__attribute__((address_space(3))) void*)l, 16, 0, 0);
}

// ---------------- prepack (layouts proven R5-R9) ----------------
// w1t : [49 s][32 o][2 half][8 j] bf16 (hi only), rows>=20 zero. 50176 B.
// midt: [29 l][4 frag: A0h,A1h,A0l,A1l][64 lane=half*32+o][8 j] bf16 = 118784 B.
__global__ void prepack(const float* __restrict__ W1,
                        const float* __restrict__ Wmid, const float* __restrict__ bmid,
                        const float* __restrict__ W30, const float* __restrict__ b30,
                        ushort_t* __restrict__ w1t, ushort_t* __restrict__ midt)
{
    const int tid = blockIdx.x * 256 + threadIdx.x;
    const int nth = gridDim.x * 256;
    for (int i = tid; i < 49 * 512; i += nth) {
        const int j = i & 7, hf = (i >> 3) & 1, o = (i >> 4) & 31, s = i >> 9;
        const float v = (o < 20) ? W1[o * 784 + s * 16 + hf * 8 + j] : 0.f;
        w1t[i] = h16(v);
    }
    for (int e2 = tid; e2 < 29 * 64; e2 += nth) {
        const int ee = e2 & 63, l = e2 >> 6;
        const int o = ee & 31, hf = ee >> 5;
        ushort_t v[32];
#pragma unroll
        for (int i = 0; i < 32; ++i) v[i] = 0;
        const bool lastl = (l == 28);
        const int omax = lastl ? 10 : 20;
        if (o < omax) {
            const float* wr = lastl ? (W30 + o * 20) : (Wmid + l * 400 + o * 20);
            const float bias = lastl ? b30[o] : bmid[l * 20 + o];
#pragma unroll
            for (int j = 0; j < 8; ++j) {
                const float w = wr[hf * 8 + j];
                v[j]      = h16(w);
                v[16 + j] = h16(w - fh(h16(w)));
            }
            if (hf == 0) {
#pragma unroll
                for (int j = 0; j < 4; ++j) {
                    const float w = wr[16 + j];
                    v[8 + j]  = h16(w);
                    v[24 + j] = h16(w - fh(h16(w)));
                }
                v[12] = h16(bias);                   // A1h j4 (x B1h k20=1.0)
                v[13] = h16(bias - fh(h16(bias)));   // A1h j5 (x B1l k21=1.0)
            }
        }
#pragma unroll
        for (int f = 0; f < 4; ++f)
#pragma unroll
            for (int j = 0; j < 8; ++j)
                midt[l * 2048 + f * 512 + ee * 8 + j] = v[f * 8 + j];
    }
}

// ---------------- fused main: barrier-free DEPTH-3 per-wave pipeline ----------------
// Block = 4 waves, 128 rows; wave wv owns rows [wv*32,+32), private 4-buffer LDS ring
// (4 x 4 KB) + private 2 KB tail. Per phase: issue {4 DMA + 2 A-loads} for phase p+3,
// then s_waitcnt vmcnt(18) (= 3 phases x 6 VMEM in flight) -> phase p landed.
// A-fragments kept in a 4-slot register ring (all indices compile-time).
// No s_barrier anywhere; WAR by program order, RAW by counted vmcnt. K-order matches
// R8/R9 -> bit-identical output.
__global__ __launch_bounds__(256, 2)
void mlp_main(const float* __restrict__ x, const float* __restrict__ b1,
              const ushort_t* __restrict__ w1t, const ushort_t* __restrict__ midt,
              float* __restrict__ out, int nrows)
{
    __shared__ float xt[4][4096];     // 4 x 16 KB: per wave 4 KB = [32 rows][8 units][4 f]
    __shared__ float xtail[2048];     // 8 KB: per wave 2 KB = [32 rows][4 units][4 f]

    const int tid  = threadIdx.x;
    const int lane = tid & 63;
    const int wv   = tid >> 6;
    const int r0   = blockIdx.x * 128;
    if (r0 >= nrows) return;
    const int colr = lane & 31;
    const int half = lane >> 5;
    const int rsw  = colr & 7;                // swizzle key for reads
    const int row  = r0 + wv * 32 + colr;     // global batch row
    const int rw0  = r0 + wv * 32;            // wave's first row

#define ISSUE_PHASE(PH, BUF) do {                                          \
        char* _lb = (char*)&xt[(BUF)][wv * 1024];                          \
        const int _pc = (PH) * 32;                                         \
        _Pragma("unroll")                                                  \
        for (int k = 0; k < 4; ++k) {                                      \
            const int slot = k * 64 + lane;          /* 0..255 */          \
            const int rl = slot >> 3, gs = slot & 7;                       \
            const int g = gs ^ (rl & 7);                                   \
            const size_t gr = (size_t)((rw0 + rl < nrows) ? (rw0 + rl) : (nrows - 1)); \
            dma16(x + gr * 784 + _pc + g * 4, _lb + k * 1024);             \
        }                                                                  \
    } while (0)

#define ALOAD(IP, ISLOT) do {                                              \
        const ushort_t* _ab = w1t + ((IP) * 2) * 512 + colr * 16 + half * 8; \
        A0r[(ISLOT)] = ld8(_ab);                                           \
        A1r[(ISLOT)] = ld8(_ab + 512);                                     \
    } while (0)

#define PHASE(P, SLOT, IP, ISLOT, VMSTR) do {                              \
        if ((IP) >= 0) { ISSUE_PHASE((IP), (ISLOT)); ALOAD((IP), (ISLOT)); } \
        __builtin_amdgcn_sched_barrier(0);                                 \
        asm volatile("s_waitcnt vmcnt(" VMSTR ")" ::: "memory");           \
        __builtin_amdgcn_sched_barrier(0);                                 \
        {                                                                  \
            const float* _xl = &xt[(SLOT)][wv * 1024 + colr * 32];         \
            _Pragma("unroll")                                              \
            for (int s = 0; s < 2; ++s) {                                  \
                const int g = s * 4 + half * 2;                            \
                const float4 va = *(const float4*)&_xl[((g)     ^ rsw) * 4]; \
                const float4 vb = *(const float4*)&_xl[((g + 1) ^ rsw) * 4]; \
                const short8 B = mk8(packhi2(va.x, va.y), packhi2(va.z, va.w), \
                                     packhi2(vb.x, vb.y), packhi2(vb.z, vb.w)); \
                acc = MFMA(s == 0 ? A0r[(SLOT)] : A1r[(SLOT)], B, acc);    \
            }                                                              \
        }                                                                  \
    } while (0)

    short8 A0r[4], A1r[4];     // register ring, constant-indexed only
    f32x16 acc;
#pragma unroll
    for (int r = 0; r < 16; ++r) acc[r] = 0.f;

    // ---- prologue: tail (2 DMA) then phases 0..2 ({4 DMA + 2 A} each) ----
#pragma unroll
    for (int k = 0; k < 2; ++k) {
        const int slot = k * 64 + lane;               // 0..127
        const int rl = slot >> 2, u = slot & 3;
        const size_t gr = (size_t)((rw0 + rl < nrows) ? (rw0 + rl) : (nrows - 1));
        dma16(x + gr * 784 + 768 + u * 4, (char*)xtail + wv * 2048 + k * 1024);
    }
    __builtin_amdgcn_sched_barrier(0);
    ISSUE_PHASE(0, 0); ALOAD(0, 0);
    __builtin_amdgcn_sched_barrier(0);
    ISSUE_PHASE(1, 1); ALOAD(1, 1);
    __builtin_amdgcn_sched_barrier(0);
    ISSUE_PHASE(2, 2); ALOAD(2, 2);
    // outstanding: 2 (tail) + 18 = 20

    // ---- 24 phases, depth-3 ----
#pragma unroll 1
    for (int pb = 0; pb < 5; ++pb) {
        const int p0 = pb * 4;
        PHASE(p0 + 0, 0, p0 + 3, 3, "18");
        PHASE(p0 + 1, 1, p0 + 4, 0, "18");
        PHASE(p0 + 2, 2, p0 + 5, 1, "18");
        PHASE(p0 + 3, 3, p0 + 6, 2, "18");
    }
    PHASE(20, 0, 23, 3, "18");
    PHASE(21, 1, -1, 0, "12");
    PHASE(22, 2, -1, 0, "6");
    PHASE(23, 3, -1, 0, "0");

    // ---- tail K-step: cols 768..783 (drained by vmcnt(0)) ----
    {
        const short8 At = ld8(w1t + 48 * 512 + colr * 16 + half * 8);
        const float* tl = &xtail[wv * 512 + colr * 16];
        const float4 va = ldf4(&tl[(half * 2) * 4]);
        const float4 vb = ldf4(&tl[(half * 2 + 1) * 4]);
        const short8 B = mk8(packhi2(va.x, va.y), packhi2(va.z, va.w),
                             packhi2(vb.x, vb.y), packhi2(vb.z, vb.w));
        acc = MFMA(At, B, acc);
    }

    // ---- bias + relu (pad rows o>=20 get acc=0 from zeroed w1t rows) ----
    float Hv[16];
#pragma unroll
    for (int r = 0; r < 16; ++r) {
        const int o = (r & 3) + 8 * (r >> 2) + 4 * half;
        Hv[r] = fmaxf(acc[r] + b1[o < 20 ? o : 0], 0.f);
    }

    // ---- fc2..fc30: prepacked A hi/lo + bias-in-k, H hi/lo (proven) ----
    const ushort_t* ap = midt + lane * 8;
#pragma unroll 1
    for (int l = 0; l < 29; ++l) {
        const short8 A0h = ld8(ap + l * 2048);
        const short8 A1h = ld8(ap + l * 2048 + 512);
        const short8 A0l = ld8(ap + l * 2048 + 1024);
        const short8 A1l = ld8(ap + l * 2048 + 1536);

        unsigned plo0 = packhi2(Hv[0], Hv[1]), plo1 = packhi2(Hv[2], Hv[3]);
        unsigned phi0 = packhi2(Hv[4], Hv[5]), phi1 = packhi2(Hv[6], Hv[7]);
        plswap(plo0, phi0); plswap(plo1, phi1);
        const short8 B0h = mk8(plo0, plo1, phi0, phi1);

        unsigned qlo0 = packhi2(lopart(Hv[0]), lopart(Hv[1]));
        unsigned qlo1 = packhi2(lopart(Hv[2]), lopart(Hv[3]));
        unsigned qhi0 = packhi2(lopart(Hv[4]), lopart(Hv[5]));
        unsigned qhi1 = packhi2(lopart(Hv[6]), lopart(Hv[7]));
        plswap(qlo0, qhi0); plswap(qlo1, qhi1);
        const short8 B0l = mk8(qlo0, qlo1, qhi0, qhi1);

        const short8 B1h = mk8(half ? 0u : packhi2(Hv[8], Hv[9]),
                               half ? 0u : packhi2(Hv[10], Hv[11]),
                               half ? 0u : 0x00003F80u, 0u);
        const short8 B1l = mk8(half ? 0u : packhi2(lopart(Hv[8]), lopart(Hv[9])),
                               half ? 0u : packhi2(lopart(Hv[10]), lopart(Hv[11])),
                               half ? 0u : 0x3F800000u, 0u);

        f32x16 d;
#pragma unroll
        for (int r = 0; r < 16; ++r) d[r] = 0.f;
        d = MFMA(A0h, B0h, d);
        d = MFMA(A0l, B0h, d);
        d = MFMA(A0h, B0l, d);
        d = MFMA(A1h, B1h, d);
        d = MFMA(A1l, B1h, d);
        d = MFMA(A1h, B1l, d);

        if (l < 28) {
#pragma unroll
            for (int r = 0; r < 16; ++r) Hv[r] = fmaxf(d[r], 0.f);
        } else {
            if (row < nrows) {
#pragma unroll
                for (int r = 0; r < 16; ++r) {
                    const int o = (r & 3) + 8 * (r >> 2) + 4 * half;
                    if (o < 10) out[(size_t)row * 10 + o] = d[r];
                }
            }
        }
    }
#undef PHASE
#undef ALOAD
#undef ISSUE_PHASE
}

extern "C" void kernel_launch(void* const* d_in, const int* in_sizes, int n_in,
                              void* d_out, int out_size, void* d_ws, size_t ws_size,
                              hipStream_t stream)
{
    const float* x    = (const float*)d_in[0];
    const float* W1   = (const float*)d_in[1];
    const float* b1   = (const float*)d_in[2];
    const float* Wmid = (const float*)d_in[3];
    const float* bmid = (const float*)d_in[4];
    const float* W30  = (const float*)d_in[5];
    const float* b30  = (const float*)d_in[6];
    float* out = (float*)d_out;

    ushort_t* w1t  = (ushort_t*)d_ws;                       // 50176 B
    ushort_t* midt = (ushort_t*)((char*)d_ws + 50176);      // 118784 B

    const int nrows = in_sizes[0] / 784;
    prepack<<<32, 256, 0, stream>>>(W1, Wmid, bmid, W30, b30, w1t, midt);
    const int grid = (nrows + 127) / 128;                   // 512 blocks, 2/CU
    mlp_main<<<grid, 256, 0, stream>>>(x, b1, w1t, midt, out, nrows);
}